// Round 6
// baseline (737.425 us; speedup 1.0000x reference)
//
#include <hip/hip_runtime.h>
#include <stdint.h>

// Problem constants (f32 world)
#define R_ 8
#define B_ 8
#define L_ 4096
#define D_ 128
#define C_ 64             // N_HASHES
#define ROWS_BL 32768     // B_*L_
// d_out: f32 [x_sorted 33,554,432][sorted_hashes 262,144][sorted_indices 262,144]
#define XS_ELEMS 33554432
#define HS_ELEMS 262144

// Scratch inside x_sorted output region (dead until kgather, byte offsets):
#define XH_OFF   0u               // 32768*128 bf16 = 8 MB
#define XL_OFF   8388608u         // 8 MB
#define WH_OFF   16777216u        // 512*128 bf16 = 128 KB
#define WL_OFF   16908288u
#define RINV_OFF 17039360u        // 32768 f32
#define CNT_OFF  17170432u        // u32
#define LIST_OFF 17170496u        // 262144 u32 (max possible flags)

typedef __attribute__((ext_vector_type(8))) short short8;
typedef __attribute__((ext_vector_type(4))) float f32x4;

__device__ __forceinline__ uint16_t f32_to_bf16_rne(float f) {
    uint32_t u; __builtin_memcpy(&u, &f, 4);
    return (uint16_t)((u + 0x7FFFu + ((u >> 16) & 1u)) >> 16);
}
__device__ __forceinline__ float bf16_to_f32(uint16_t h) {
    uint32_t t = ((uint32_t)h) << 16; float f; __builtin_memcpy(&f, &t, 4); return f;
}

// Prep A: per 64-row tile: coalesced read, f32 sq-norm (LDS atomic; used only to
// SCALE the margin, tiny nondeterminism harmless), bf16 hi/lo split -> global.
__global__ __launch_bounds__(256) void kprep_x(const float* __restrict__ x,
                                               uint16_t* __restrict__ xh,
                                               uint16_t* __restrict__ xl,
                                               float* __restrict__ rinv,
                                               uint32_t* __restrict__ cnt) {
    int rowbase = blockIdx.x * 64;
    int t = threadIdx.x;
    __shared__ float snorm[64];
    if (t < 64) snorm[t] = 0.f;
    if (blockIdx.x == 0 && t == 0) *cnt = 0u;
    __syncthreads();
#pragma unroll
    for (int p = 0; p < 8; ++p) {
        int idx = p * 256 + t;            // 2048 float4 granules = 64 rows * 32
        int row = idx >> 5, off = idx & 31;
        float4 v = ((const float4*)x)[(size_t)(rowbase + row) * 32 + off];
        float sq = v.x*v.x + v.y*v.y + v.z*v.z + v.w*v.w;
        atomicAdd(&snorm[row], sq);
        uint16_t h0 = f32_to_bf16_rne(v.x), h1 = f32_to_bf16_rne(v.y);
        uint16_t h2 = f32_to_bf16_rne(v.z), h3 = f32_to_bf16_rne(v.w);
        ushort4 hh = { h0, h1, h2, h3 };
        ushort4 ll = { f32_to_bf16_rne(v.x - bf16_to_f32(h0)),
                       f32_to_bf16_rne(v.y - bf16_to_f32(h1)),
                       f32_to_bf16_rne(v.z - bf16_to_f32(h2)),
                       f32_to_bf16_rne(v.w - bf16_to_f32(h3)) };
        size_t o = (size_t)(rowbase + row) * 128 + off * 4;
        *(ushort4*)(xh + o) = hh;
        *(ushort4*)(xl + o) = ll;
    }
    __syncthreads();
    if (t < 64) rinv[rowbase + t] = 1.0f / sqrtf(fmaxf(snorm[t], 1e-30f));
}

// Prep B: w[512][128] (= rm[:8] flattened) bf16 hi/lo split.
__global__ __launch_bounds__(256) void kprep_w(const float* __restrict__ rm,
                                               uint16_t* __restrict__ wh,
                                               uint16_t* __restrict__ wl) {
    int i = blockIdx.x * 256 + threadIdx.x;   // 4096 float4 granules
    float4 v = ((const float4*)rm)[i];
    uint16_t h0 = f32_to_bf16_rne(v.x), h1 = f32_to_bf16_rne(v.y);
    uint16_t h2 = f32_to_bf16_rne(v.z), h3 = f32_to_bf16_rne(v.w);
    ushort4 hh = { h0, h1, h2, h3 };
    ushort4 ll = { f32_to_bf16_rne(v.x - bf16_to_f32(h0)),
                   f32_to_bf16_rne(v.y - bf16_to_f32(h1)),
                   f32_to_bf16_rne(v.z - bf16_to_f32(h2)),
                   f32_to_bf16_rne(v.w - bf16_to_f32(h3)) };
    *(ushort4*)(wh + (size_t)i * 4) = hh;
    *(ushort4*)(wl + (size_t)i * 4) = ll;
}

// Tier-1 MFMA kernel: block = 256 rows x 64 cols (one r), K=384 virtual
// (xh*wh, xh*wl, xl*wh in 12 ksteps of 32). Epilogue: rot tile -> LDS
// (XOR-swizzled), serial first-wins +/- scan per row, margin test, flag list.
__global__ __launch_bounds__(256) void kmfma(const uint16_t* __restrict__ xh,
                                             const uint16_t* __restrict__ xl,
                                             const uint16_t* __restrict__ wh,
                                             const uint16_t* __restrict__ wl,
                                             const float* __restrict__ rinv,
                                             uint16_t* __restrict__ hws,
                                             uint32_t* __restrict__ cnt,
                                             uint32_t* __restrict__ list) {
    __shared__ alignas(16) char smem[65536];
    uint16_t* As[2] = { (uint16_t*)smem, (uint16_t*)(smem + 16384) };   // [256][32]
    uint16_t* Bs[2] = { (uint16_t*)(smem + 32768), (uint16_t*)(smem + 36864) }; // [64][32]

    int rowbase = blockIdx.x * 256;
    int r = blockIdx.y;
    int t = threadIdx.x;
    int wv = t >> 6, l = t & 63;
    int lr = l & 15, kg = l >> 4;

    f32x4 acc[4][4];
#pragma unroll
    for (int a = 0; a < 4; ++a)
#pragma unroll
        for (int b = 0; b < 4; ++b) acc[a][b] = (f32x4){0.f, 0.f, 0.f, 0.f};

    // staging helper (plain loads; src per kstep)
    auto stage = [&](int ks, int buf) {
        int seg = ks >> 2, pk0 = (ks & 3) * 32;
        const uint16_t* aq = (seg < 2) ? xh : xl;
        const uint16_t* bq = (seg == 1) ? wl : wh;
#pragma unroll
        for (int p = 0; p < 4; ++p) {
            int idx = p * 256 + t;            // 1024 granules: 256 rows x 4
            int row = idx >> 2, k4 = idx & 3;
            uint4 v = *(const uint4*)(aq + (size_t)(rowbase + row) * 128 + pk0 + k4 * 8);
            *(uint4*)(As[buf] + idx * 8) = v;
        }
        {   // B: 256 granules: 64 cols x 4
            int col = t >> 2, k4 = t & 3;
            uint4 v = *(const uint4*)(bq + (size_t)(r * 64 + col) * 128 + pk0 + k4 * 8);
            *(uint4*)(Bs[buf] + t * 8) = v;
        }
    };

    stage(0, 0);
    for (int ks = 0; ks < 12; ++ks) {
        __syncthreads();
        if (ks < 11) stage(ks + 1, (ks + 1) & 1);
        const uint16_t* Ab = As[ks & 1];
        const uint16_t* Bb = Bs[ks & 1];
        short8 bfrag[4];
#pragma unroll
        for (int ct = 0; ct < 4; ++ct)
            bfrag[ct] = *(const short8*)(Bb + (ct * 16 + lr) * 32 + kg * 8);
#pragma unroll
        for (int rt = 0; rt < 4; ++rt) {
            short8 a = *(const short8*)(Ab + (wv * 64 + rt * 16 + lr) * 32 + kg * 8);
#pragma unroll
            for (int ct = 0; ct < 4; ++ct)
                acc[rt][ct] = __builtin_amdgcn_mfma_f32_16x16x32_bf16(
                    a, bfrag[ct], acc[rt][ct], 0, 0, 0);
        }
    }
    __syncthreads();   // stage buffers dead; reuse LDS as rot tiles

    float* rot = (float*)smem + wv * 4096;     // per-wave [64][64], XOR swizzle
#pragma unroll
    for (int rt = 0; rt < 4; ++rt)
#pragma unroll
        for (int ct = 0; ct < 4; ++ct)
#pragma unroll
            for (int reg = 0; reg < 4; ++reg) {
                int row = rt * 16 + kg * 4 + reg;
                int c = ct * 16 + lr;
                rot[row * 64 + (c ^ (row & 31))] = acc[rt][ct][reg];
            }
    __syncthreads();

    // scan: lane l owns row l of its wave (serial first-wins over the +/- concat)
    int grow = rowbase + wv * 64 + l;
    float ri = rinv[grow];
    float m1 = -__builtin_inff(), m2 = -__builtin_inff();
    int i1 = 0;
    const float* rr = rot + l * 64;
    for (int c = 0; c < C_; ++c) {
        float v = rr[c ^ (l & 31)];
        if (v > m1)      { m2 = m1; m1 = v; i1 = c; }
        else if (v > m2) { m2 = v; }
        float nv = -v;
        if (nv > m1)       { m2 = m1; m1 = nv; i1 = C_ + c; }
        else if (nv > m2)  { m2 = nv; }
    }
    hws[((size_t)r << 15) + grow] = (uint16_t)i1;
    float gap = m1 - m2;
    if (!(gap * ri >= 1e-4f)) {                // includes NaN/tie safety
        uint32_t e = atomicAdd(cnt, 1u);
        list[e] = (uint32_t)grow | ((uint32_t)r << 15);
    }
}

// Exact f64 fallback (verbatim round-4/5 numerics, proven absmax 0) over the
// compacted flag list; overwrites hws entries.
__global__ __launch_bounds__(256) void kfallback(const float* __restrict__ x,
                                                 const float* __restrict__ rm,
                                                 const uint32_t* __restrict__ list,
                                                 const uint32_t* __restrict__ cnt,
                                                 uint16_t* __restrict__ hws) {
    uint32_t n = *cnt;
    for (uint32_t e = blockIdx.x * 256 + threadIdx.x; e < n; e += 256u * 256u) {
        uint32_t ent = list[e];
        int row = ent & 32767, r = ent >> 15;
        const float* xr = x + (size_t)row * D_;
        float xv[128];
#pragma unroll
        for (int d = 0; d < D_; ++d) xv[d] = xr[d];
        double n0 = 0.0, n1 = 0.0, n2 = 0.0, n3 = 0.0;
#pragma unroll
        for (int d = 0; d < D_; d += 4) {
            double v0 = (double)xv[d+0], v1 = (double)xv[d+1];
            double v2 = (double)xv[d+2], v3 = (double)xv[d+3];
            n0 = fma(v0, v0, n0); n1 = fma(v1, v1, n1);
            n2 = fma(v2, v2, n2); n3 = fma(v3, v3, n3);
        }
        double norm = sqrt((n0 + n1) + (n2 + n3));
        if (norm < 1e-12) norm = 1e-12;
        double rv = 1.0 / norm;
        const float* w = rm + (size_t)r * (C_ * D_);
        double bp = -1e300, bn = -1e300;
        int bpi = 0, bni = 0;
        for (int c = 0; c < C_; ++c) {
            const float* wc = w + (c << 7);
            double a0 = 0.0, a1 = 0.0, a2 = 0.0, a3 = 0.0;
#pragma unroll
            for (int j = 0; j < 128; j += 4) {
                a0 = fma((double)xv[j+0] * rv, (double)wc[j+0], a0);
                a1 = fma((double)xv[j+1] * rv, (double)wc[j+1], a1);
                a2 = fma((double)xv[j+2] * rv, (double)wc[j+2], a2);
                a3 = fma((double)xv[j+3] * rv, (double)wc[j+3], a3);
            }
            double v = (a0 + a1) + (a2 + a3);
            if (v > bp)  { bp = v;  bpi = c; }
            if (-v > bn) { bn = -v; bni = c; }
        }
        hws[((size_t)r << 15) + row] = (uint16_t)((bp >= bn) ? bpi : (C_ + bni));
    }
}

// Stable counting sort per (r,b) (unchanged, proven).
__global__ __launch_bounds__(256) void ksort(uint16_t* __restrict__ hws,
                                             float* __restrict__ out) {
    int rb = blockIdx.x;
    int t = threadIdx.x;
    __shared__ uint16_t h[4096];
    __shared__ uint16_t cnt[64 * 128];
    __shared__ uint16_t inv[4096];
    __shared__ int base[128];
    uint16_t* slice = hws + ((size_t)rb << 12);
    for (int i = t; i < 4096; i += 256) h[i] = slice[i];
    for (int i = t; i < 8192; i += 256) cnt[i] = 0;
    __syncthreads();
    if (t < 64) {
        uint16_t* c = cnt + (t << 7);
        const uint16_t* hh = h + (t << 6);
        for (int i = 0; i < 64; ++i) c[hh[i] & 127]++;
    }
    __syncthreads();
    if (t < 128) {
        int run = 0;
        for (int ch = 0; ch < 64; ++ch) {
            int v = cnt[(ch << 7) + t];
            cnt[(ch << 7) + t] = (uint16_t)run;
            run += v;
        }
        base[t] = run;
    }
    __syncthreads();
    if (t == 0) {
        int run = 0;
        for (int bin = 0; bin < 128; ++bin) { int v = base[bin]; base[bin] = run; run += v; }
    }
    __syncthreads();
    if (t < 64) {
        uint16_t* c = cnt + (t << 7);
        const uint16_t* hh = h + (t << 6);
        int p0 = t << 6;
        for (int i = 0; i < 64; ++i) {
            int bin = hh[i] & 127;
            int dest = base[bin] + c[bin];
            c[bin]++;
            inv[dest] = (uint16_t)(p0 + i);
        }
    }
    __syncthreads();
    float* out_h = out + XS_ELEMS;
    float* out_i = out + XS_ELEMS + HS_ELEMS;
    int obase = rb << 12;
    for (int dst = t; dst < 4096; dst += 256) {
        int p = inv[dst];
        out_h[obase + dst] = (float)((h[p] & 127) + 1);
        out_i[obase + dst] = (float)p;
        slice[dst] = (uint16_t)p;
    }
}

// Gather x rows (f32 bit-exact), one float4 per thread (unchanged, proven).
__global__ void kgather(const float* __restrict__ x,
                        const uint16_t* __restrict__ inv,
                        float4* __restrict__ outx) {
    int id = blockIdx.x * 256 + threadIdx.x;
    int lane = id & 31;
    int rowg = id >> 5;
    int b = (rowg >> 12) & 7;
    int src = inv[rowg] & 4095;
    const float4* xp = (const float4*)x;
    outx[id] = xp[((size_t)((b << 12) + src) << 5) + lane];
}

extern "C" void kernel_launch(void* const* d_in, const int* in_sizes, int n_in,
                              void* d_out, int out_size, void* d_ws, size_t ws_size,
                              hipStream_t stream) {
    const float* x  = (const float*)d_in[0];    // (8,4096,128) f32
    const float* rm = (const float*)d_in[1];    // (16,64,128) f32
    float* out = (float*)d_out;
    char* ob = (char*)d_out;
    uint16_t* xh  = (uint16_t*)(ob + XH_OFF);
    uint16_t* xl  = (uint16_t*)(ob + XL_OFF);
    uint16_t* wh  = (uint16_t*)(ob + WH_OFF);
    uint16_t* wl  = (uint16_t*)(ob + WL_OFF);
    float*    riv = (float*)(ob + RINV_OFF);
    uint32_t* cnt = (uint32_t*)(ob + CNT_OFF);
    uint32_t* lst = (uint32_t*)(ob + LIST_OFF);
    uint16_t* hws = (uint16_t*)d_ws;            // 512 KB proven region

    kprep_x<<<dim3(512), 256, 0, stream>>>(x, xh, xl, riv, cnt);
    kprep_w<<<dim3(16), 256, 0, stream>>>(rm, wh, wl);
    kmfma<<<dim3(128, R_), 256, 0, stream>>>(xh, xl, wh, wl, riv, hws, cnt, lst);
    kfallback<<<dim3(256), 256, 0, stream>>>(x, rm, lst, cnt, hws);
    ksort<<<dim3(64), 256, 0, stream>>>(hws, out);
    kgather<<<dim3(32768), 256, 0, stream>>>(x, hws, (float4*)out);
}